// Round 5
// baseline (349.414 us; speedup 1.0000x reference)
//
#include <hip/hip_runtime.h>
#include <stdint.h>

#define T_  4096
#define GS  296   // xsr g-stride (floats); %32 = 8 -> 2-way max
#define US  16    // xsr u-stride (floats)
#define AJ  652   // As j-stride (u16): 1304B, 8B-aligned; word stride 326%32=6
#define AT  40    // As tp-stride (u16)
#define CJ  260   // Cs j-stride (u16): word stride 130%32=2

static __device__ __forceinline__ float bflo(uint32_t w){ union{uint32_t u;float f;}v; v.u=w<<16; return v.f; }
static __device__ __forceinline__ float bfhi(uint32_t w){ union{uint32_t u;float f;}v; v.u=w&0xFFFF0000u; return v.f; }
static __device__ __forceinline__ uint16_t f2bf(float f){
    union{float f;uint32_t u;}v; v.f=f; uint32_t x=v.u;
    return (uint16_t)((x + 0x7FFFu + ((x>>16)&1u)) >> 16);
}

__global__ __launch_bounds__(1024, 2)
void tamcad_kernel(const float* __restrict__ x, const float* __restrict__ W,
                   const float* __restrict__ bias, float* __restrict__ out)
{
    __shared__ float    xsr[32*GS];   // 37,888 B; x slab / skewed out-stage
    __shared__ uint16_t As [64*AJ];   // 83,456 B; A[j*AJ + tp*AT + i] (bf16)
    __shared__ uint16_t Cs [64*CJ];   // 33,280 B; C[j*CJ + tp*16 + d] (bf16)

    const int tid   = threadIdx.x;
    const int bk    = blockIdx.x >> 5;   // 0..7
    const int chunk = blockIdx.x & 31;   // 0..31
    const int b     = bk >> 1;
    const int k     = bk & 1;

    // P1 mapping: 32 lanes per group, 3 o's per thread
    const int oq   = tid & 31;
    const int g    = tid >> 5;           // 0..31
    const int slot = oq >> 4;            // 0: t, 1: t+1

    // P0 mapping
    const int dl = tid & 15;
    const int gl = (tid >> 4) & 31;
    const int hl = tid >> 9;             // 0: u0..7, 1: u8..16

    // ---- per-thread W rows (3 x 16), bias, routing ----
    float wreg[3][16], breg[3];
    int aoff[3], coff[3]; bool isl[3];
    #pragma unroll
    for (int r = 0; r < 3; ++r) {
        const int o = oq*3 + r;
        const float4* wp = reinterpret_cast<const float4*>(W + (((size_t)(k*32+g))*96 + o)*16);
        float4 w0=wp[0], w1=wp[1], w2=wp[2], w3=wp[3];
        wreg[r][ 0]=w0.x; wreg[r][ 1]=w0.y; wreg[r][ 2]=w0.z; wreg[r][ 3]=w0.w;
        wreg[r][ 4]=w1.x; wreg[r][ 5]=w1.y; wreg[r][ 6]=w1.z; wreg[r][ 7]=w1.w;
        wreg[r][ 8]=w2.x; wreg[r][ 9]=w2.y; wreg[r][10]=w2.z; wreg[r][11]=w2.w;
        wreg[r][12]=w3.x; wreg[r][13]=w3.y; wreg[r][14]=w3.z; wreg[r][15]=w3.w;
        breg[r] = bias[(k*32+g)*96 + o];
        if (o < 32)      { isl[r]=true;  aoff[r]=o*AJ + g;            coff[r]=0; }
        else if (o < 48) { isl[r]=false; coff[r]=g*CJ + (o-32);       aoff[r]=0; }
        else if (o < 80) { isl[r]=true;  aoff[r]=(o-16)*AJ + g;       coff[r]=0; }
        else             { isl[r]=false; coff[r]=(32+g)*CJ + (o-80);  aoff[r]=0; }
    }

    const float* xrow = x + ((size_t)b*1024 + (size_t)(k*32+gl)*16 + dl) * (size_t)T_;

    // ---- register prefetch of the first x slab ----
    float4 pA, pB; float pS = 0.0f;
    {
        const float* gp = xrow + chunk*128 + hl*8;
        pA = *(const float4*)(gp + 0);
        pB = *(const float4*)(gp + 4);
        pS = (hl && (chunk*128 + 16) < T_) ? gp[8] : 0.0f;
    }

    for (int l = 0; l < 8; ++l) {
        const int t0 = chunk*128 + l*16;

        // ---- P0: spill prefetched regs into xsr[g][u][d] ----
        {
            float* xp = xsr + gl*GS + dl;
            const int ub = hl*8;
            xp[(ub+0)*US]=pA.x; xp[(ub+1)*US]=pA.y; xp[(ub+2)*US]=pA.z; xp[(ub+3)*US]=pA.w;
            xp[(ub+4)*US]=pB.x; xp[(ub+5)*US]=pB.y; xp[(ub+6)*US]=pB.z; xp[(ub+7)*US]=pB.w;
            if (hl) xp[16*US] = pS;
        }
        __syncthreads();

        // issue next tile's loads; in flight across P1/P3/P4
        if (l < 7) {
            const int t0n = t0 + 16;
            const float* gp = xrow + t0n + hl*8;
            pA = *(const float4*)(gp + 0);
            pB = *(const float4*)(gp + 4);
            pS = (hl && (t0n + 16) < T_) ? gp[8] : 0.0f;
        }

        // ---- P1: y = W·x + b; softmax with 8-wide batched shuffle reduction ----
        #pragma unroll
        for (int th = 0; th < 2; ++th) {
            float ev0[8], ev1[8], ev2[8], asum[8];
            #pragma unroll
            for (int q = 0; q < 8; ++q) {
                const int tp = th*8 + q;
                float xv[16];
                {
                    const float4* p4 = reinterpret_cast<const float4*>(xsr + g*GS + (tp+slot)*US);
                    float4 A0=p4[0], A1=p4[1], A2=p4[2], A3=p4[3];
                    xv[ 0]=A0.x; xv[ 1]=A0.y; xv[ 2]=A0.z; xv[ 3]=A0.w;
                    xv[ 4]=A1.x; xv[ 5]=A1.y; xv[ 6]=A1.z; xv[ 7]=A1.w;
                    xv[ 8]=A2.x; xv[ 9]=A2.y; xv[10]=A2.z; xv[11]=A2.w;
                    xv[12]=A3.x; xv[13]=A3.y; xv[14]=A3.z; xv[15]=A3.w;
                }
                float y0 = breg[0], y1 = breg[1], y2 = breg[2];
                #pragma unroll
                for (int d = 0; d < 16; ++d) {
                    y0 = fmaf(wreg[0][d], xv[d], y0);
                    y1 = fmaf(wreg[1][d], xv[d], y1);
                    y2 = fmaf(wreg[2][d], xv[d], y2);
                }
                // no-max softmax (|y| <~ 8, fp32-safe)
                const float e0 = __expf(y0), e1 = __expf(y1), e2 = __expf(y2);
                asum[q] = (isl[0]?e0:0.f) + (isl[1]?e1:0.f) + (isl[2]?e2:0.f);
                if (!isl[0]) Cs[coff[0] + tp*16] = f2bf(y0);
                if (!isl[1]) Cs[coff[1] + tp*16] = f2bf(y1);
                if (!isl[2]) Cs[coff[2] + tp*16] = f2bf(y2);
                ev0[q]=e0; ev1[q]=e1; ev2[q]=e2;
            }
            // 5 rounds x 8 independent chains (pipelined cross-lane reduce)
            #pragma unroll
            for (int s = 1; s < 32; s <<= 1) {
                #pragma unroll
                for (int q = 0; q < 8; ++q) asum[q] += __shfl_xor(asum[q], s);
            }
            #pragma unroll
            for (int q = 0; q < 8; ++q) {
                const int tp = th*8 + q;
                const float rinv = __builtin_amdgcn_rcpf(asum[q]);
                if (isl[0]) As[aoff[0] + tp*AT] = f2bf(ev0[q]*rinv);
                if (isl[1]) As[aoff[1] + tp*AT] = f2bf(ev1[q]*rinv);
                if (isl[2]) As[aoff[2] + tp*AT] = f2bf(ev2[q]*rinv);
            }
        }
        __syncthreads();

        // ---- P3: out[i][d] = sum_j A[i][j]*C[j][d]; one wave per t ----
        {
            const int t  = tid >> 6;            // 0..15
            const int r6 = tid & 63;
            const int i0 = (r6 & 7) << 2;       // 0,4,..28
            const int d0 = (r6 >> 3) << 1;      // 0,2,..14
            float acc[4][2];
            #pragma unroll
            for (int ii = 0; ii < 4; ++ii) { acc[ii][0]=0.f; acc[ii][1]=0.f; }
            const uint16_t* Ap = As + t*AT + i0;
            const uint16_t* Cp = Cs + t*16 + d0;
            #pragma unroll 8
            for (int j = 0; j < 64; ++j) {
                uint2    aw = *(const uint2*)(Ap + j*AJ);
                uint32_t cw = *(const uint32_t*)(Cp + j*CJ);
                float a0=bflo(aw.x), a1=bfhi(aw.x), a2=bflo(aw.y), a3=bfhi(aw.y);
                float c0=bflo(cw),   c1=bfhi(cw);
                acc[0][0]=fmaf(a0,c0,acc[0][0]); acc[0][1]=fmaf(a0,c1,acc[0][1]);
                acc[1][0]=fmaf(a1,c0,acc[1][0]); acc[1][1]=fmaf(a1,c1,acc[1][1]);
                acc[2][0]=fmaf(a2,c0,acc[2][0]); acc[2][1]=fmaf(a2,c1,acc[2][1]);
                acc[3][0]=fmaf(a3,c0,acc[3][0]); acc[3][1]=fmaf(a3,c1,acc[3][1]);
            }
            const int skew = i0;                // == (row>>6)*4 for all rows written
            #pragma unroll
            for (int ii = 0; ii < 4; ++ii)
                #pragma unroll
                for (int dd = 0; dd < 2; ++dd) {
                    const int row = (i0+ii)*16 + d0+dd;
                    xsr[row*17 + skew + t] = acc[ii][dd];
                }
        }
        __syncthreads();

        // ---- P4: split halves; t-coalesced 64B-row global writes ----
        if (tid < 512) {
            const int skew = (tid >> 6) * 4;
            float ov[16];
            #pragma unroll
            for (int u = 0; u < 16; ++u) ov[u] = xsr[tid*17 + skew + u];
            float* op = out + ((size_t)b*1024 + k*512 + tid)*(size_t)T_ + t0;
            *(float4*)(op + 0)  = make_float4(ov[ 0],ov[ 1],ov[ 2],ov[ 3]);
            *(float4*)(op + 4)  = make_float4(ov[ 4],ov[ 5],ov[ 6],ov[ 7]);
            *(float4*)(op + 8)  = make_float4(ov[ 8],ov[ 9],ov[10],ov[11]);
            *(float4*)(op + 12) = make_float4(ov[12],ov[13],ov[14],ov[15]);
        } else {
            // 4 attn rows per thread via b64 quad reads (2 lanes/bank -> conflict-free)
            const int q  = tid - 512;
            const int j  = q & 63;
            const int i0 = (q >> 6) << 2;       // 0,4,..28
            float* attn_base = out + (size_t)4*1024*(size_t)T_;
            const uint16_t* ap = As + j*AJ + i0;
            float* tp0 = attn_base + (((size_t)bk*32 + i0)*64 + j)*(size_t)T_ + t0;
            #pragma unroll
            for (int c = 0; c < 4; ++c) {       // tp chunks of 4
                float av[4][4];
                #pragma unroll
                for (int u = 0; u < 4; ++u) {
                    uint2 aw = *(const uint2*)(ap + (c*4+u)*AT);
                    av[0][u]=bflo(aw.x); av[1][u]=bfhi(aw.x);
                    av[2][u]=bflo(aw.y); av[3][u]=bfhi(aw.y);
                }
                #pragma unroll
                for (int ii = 0; ii < 4; ++ii)
                    *(float4*)(tp0 + (size_t)ii*64*T_ + c*4) =
                        make_float4(av[ii][0],av[ii][1],av[ii][2],av[ii][3]);
            }
        }
        __syncthreads();
    }
}

extern "C" void kernel_launch(void* const* d_in, const int* in_sizes, int n_in,
                              void* d_out, int out_size, void* d_ws, size_t ws_size,
                              hipStream_t stream) {
    const float* x  = (const float*)d_in[0];
    const float* W  = (const float*)d_in[1];
    const float* bs = (const float*)d_in[2];
    float* out = (float*)d_out;
    tamcad_kernel<<<dim3(256), dim3(1024), 0, stream>>>(x, W, bs, out);
}

// Round 7
// 302.035 us; speedup vs baseline: 1.1569x; 1.1569x over previous
//
#include <hip/hip_runtime.h>
#include <stdint.h>

#define T_   4096
#define XGS  140            // xs g-stride in u32 (17 u-slots * 8 d-pairs + 4 pad)
#define AIS  66             // As i-stride (u16): 64 j + 2 pad
#define ATS  2112           // As t-stride (u16) = 32*66
#define CDS  66             // Cs d-stride (u16)
#define CTS  1056           // Cs t-stride (u16) = 16*66
#define CSB  (16*ATS)       // Cs base offset within ACs (u16)
#define RSW  33             // rs t-stride (f32)

typedef _Float16 h2 __attribute__((ext_vector_type(2)));

static __device__ __forceinline__ float dot2(uint32_t a, uint32_t b, float c) {
#if __has_builtin(__builtin_amdgcn_fdot2)
    return __builtin_amdgcn_fdot2(__builtin_bit_cast(h2, a), __builtin_bit_cast(h2, b), c, false);
#else
    h2 ha = __builtin_bit_cast(h2, a), hb = __builtin_bit_cast(h2, b);
    return fmaf((float)ha.x, (float)hb.x, fmaf((float)ha.y, (float)hb.y, c));
#endif
}
static __device__ __forceinline__ float exp2a(float x) {
#if __has_builtin(__builtin_amdgcn_exp2f)
    return __builtin_amdgcn_exp2f(x);
#else
    return exp2f(x);
#endif
}
static __device__ __forceinline__ uint16_t f2h(float f) {
    _Float16 h = (_Float16)f; return __builtin_bit_cast(uint16_t, h);
}
static __device__ __forceinline__ float h2f(uint16_t u) {
    return (float)__builtin_bit_cast(_Float16, u);
}
static __device__ __forceinline__ uint32_t pk2(float lo, float hi) {
    return __builtin_bit_cast(uint32_t, __builtin_amdgcn_cvt_pkrtz(lo, hi));
}
// out-stage skew: idx = 17*row + (row>>4) + col. INJECTIVE: for r2>r1,
// delta >= 17 while col spans only 0..15; f steps are 0/+1 per row.
// Max index 511*17 + 31 + 15 = 8733 < 8832.
static __device__ __forceinline__ int stg_idx(int row, int col) {
    return row * 17 + (row >> 4) + col;
}

__global__ __launch_bounds__(1024, 4)
void tamcad_kernel(const float* __restrict__ x, const float* __restrict__ W,
                   const float* __restrict__ bias, float* __restrict__ out)
{
    __shared__ uint32_t stg[8832];              // 35,328B: out-stage; first 4480 words = xs
    __shared__ uint16_t ACs[CSB + 16 * CTS];    // 101,376B: As | Cs (f16)
    __shared__ float    rs[16 * RSW];           // 2,112B: 16 x rcp(rowsum) per (t, i)

    uint32_t* xs32 = stg;

    const int tid   = threadIdx.x;
    const int bk    = blockIdx.x >> 5;   // 0..7
    const int chunk = blockIdx.x & 31;   // 0..31
    const int b     = bk >> 1;
    const int k     = bk & 1;

    // P1 mapping: 32 lanes per group, 3 o's per thread
    const int oq   = tid & 31;
    const int g    = tid >> 5;           // 0..31
    const int slot = oq >> 4;            // 0: u=t, 1: u=t+1

    // P0 mapping
    const int dl = tid & 15;
    const int gl = (tid >> 4) & 31;
    const int hl = tid >> 9;             // 0: u0..7, 1: u8..16

    // ---- W rows as packed f16 pairs (3 x 8 u32), bias, store routing ----
    uint32_t wp2[3][8];
    float breg[3];
    int sbase[3], sstr[3]; bool isl[3];
    #pragma unroll
    for (int r = 0; r < 3; ++r) {
        const int o = oq * 3 + r;
        const float4* wp = reinterpret_cast<const float4*>(W + (((size_t)(k * 32 + g)) * 96 + o) * 16);
        float4 w0 = wp[0], w1 = wp[1], w2 = wp[2], w3 = wp[3];
        wp2[r][0] = pk2(w0.x, w0.y); wp2[r][1] = pk2(w0.z, w0.w);
        wp2[r][2] = pk2(w1.x, w1.y); wp2[r][3] = pk2(w1.z, w1.w);
        wp2[r][4] = pk2(w2.x, w2.y); wp2[r][5] = pk2(w2.z, w2.w);
        wp2[r][6] = pk2(w3.x, w3.y); wp2[r][7] = pk2(w3.z, w3.w);
        breg[r] = bias[(k * 32 + g) * 96 + o];
        if (o < 32)      { isl[r] = true;  sbase[r] = g * AIS + o;               sstr[r] = ATS; }
        else if (o < 48) { isl[r] = false; sbase[r] = CSB + (o - 32) * CDS + g;  sstr[r] = CTS; }
        else if (o < 80) { isl[r] = true;  sbase[r] = g * AIS + (o - 16);        sstr[r] = ATS; }
        else             { isl[r] = false; sbase[r] = CSB + (o - 80) * CDS + 32 + g; sstr[r] = CTS; }
    }

    const float* xrow = x + ((size_t)b * 1024 + (size_t)(k * 32 + gl) * 16 + dl) * (size_t)T_;

    // ---- first slab prefetch: hl=0 -> u0..7, hl=1 -> u8..16 ----
    float4 pA, pB; float pS = 0.0f;
    {
        const float* gp = xrow + chunk * 128 + hl * 8;
        pA = *(const float4*)(gp + 0);
        pB = *(const float4*)(gp + 4);
        pS = (hl && (chunk * 128 + 16) < T_) ? gp[8] : 0.0f;
    }

    for (int l = 0; l < 8; ++l) {
        const int t0 = chunk * 128 + l * 16;

        // ---- P0: pack f32 pairs -> f16 and stage into xs[g][u][dpair] ----
        {
            float vals[9] = { pA.x, pA.y, pA.z, pA.w, pB.x, pB.y, pB.z, pB.w, pS };
            const int ubase = hl * 8;
            #pragma unroll
            for (int i = 0; i < 9; ++i) {
                if (i < 8 || hl) {
                    float mine  = vals[i];
                    float other = __shfl_xor(mine, 1);
                    const int u = ubase + i;
                    if (((u ^ dl) & 1) == 0) {   // even d-lane stores even u, odd stores odd u
                        uint32_t pk = (dl & 1) ? pk2(other, mine) : pk2(mine, other);
                        xs32[gl * XGS + u * 8 + (dl >> 1)] = pk;
                    }
                }
            }
        }
        __syncthreads();

        // ---- P1: y = W.x + b via dot2; store e' = exp(y)/16 (logit) or y (ctx) ----
        #pragma unroll
        for (int th = 0; th < 2; ++th) {
            float asum[8];
            #pragma unroll
            for (int q = 0; q < 8; ++q) {
                const int tp = th * 8 + q;
                const uint32_t* xp = xs32 + g * XGS + (tp + slot) * 8;
                uint4 xa = *(const uint4*)xp;
                uint4 xb = *(const uint4*)(xp + 4);
                uint32_t xw[8] = { xa.x, xa.y, xa.z, xa.w, xb.x, xb.y, xb.z, xb.w };
                float y0 = breg[0], y1 = breg[1], y2 = breg[2];
                #pragma unroll
                for (int dd = 0; dd < 8; ++dd) {
                    y0 = dot2(wp2[0][dd], xw[dd], y0);
                    y1 = dot2(wp2[1][dd], xw[dd], y1);
                    y2 = dot2(wp2[2][dd], xw[dd], y2);
                }
                // e' = 2^(y*log2e - 4) = exp(y)/16 : f16-safe to y ~ 13.9
                const float e0 = exp2a(fmaf(y0, 1.44269504089f, -4.0f));
                const float e1 = exp2a(fmaf(y1, 1.44269504089f, -4.0f));
                const float e2 = exp2a(fmaf(y2, 1.44269504089f, -4.0f));
                asum[q] = (isl[0] ? e0 : 0.f) + (isl[1] ? e1 : 0.f) + (isl[2] ? e2 : 0.f);
                ACs[sbase[0] + tp * sstr[0]] = f2h(isl[0] ? e0 : y0);
                ACs[sbase[1] + tp * sstr[1]] = f2h(isl[1] ? e1 : y1);
                ACs[sbase[2] + tp * sstr[2]] = f2h(isl[2] ? e2 : y2);
            }
            #pragma unroll
            for (int s = 1; s < 32; s <<= 1) {
                #pragma unroll
                for (int q = 0; q < 8; ++q) asum[q] += __shfl_xor(asum[q], s);
            }
            if (oq == 0) {
                #pragma unroll
                for (int q = 0; q < 8; ++q)
                    rs[(th * 8 + q) * RSW + g] = __builtin_amdgcn_rcpf(asum[q]);
            }
        }
        __syncthreads();

        // issue next tile's global loads; land during P3/P4
        if (l < 7) {
            const int t0n = t0 + 16;
            const float* gp = xrow + t0n + hl * 8;
            pA = *(const float4*)(gp + 0);
            pB = *(const float4*)(gp + 4);
            pS = (hl && (t0n + 16) < T_) ? gp[8] : 0.0f;
        }

        // ---- P3: out[i][d] = (sum_jp dot2(A,C)) * rinv ; one 64-lane slice per t ----
        {
            const int t  = tid >> 6;             // 0..15
            const int r6 = tid & 63;
            const int i0 = (r6 & 15) * 2;        // 0,2,..,30
            const int d0 = (r6 >> 4) * 4;        // 0,4,8,12
            const uint32_t* Aw = (const uint32_t*)ACs;
            const uint32_t* Cw = (const uint32_t*)(ACs + CSB);
            const int abase = t * 1056 + i0 * 33;
            const int cbase = t * 528 + d0 * 33;
            float acc[2][4];
            #pragma unroll
            for (int ii = 0; ii < 2; ++ii)
                #pragma unroll
                for (int dd = 0; dd < 4; ++dd) acc[ii][dd] = 0.f;
            #pragma unroll 8
            for (int jp = 0; jp < 32; ++jp) {
                uint32_t a0 = Aw[abase + jp],      a1 = Aw[abase + 33 + jp];
                uint32_t c0 = Cw[cbase + jp],      c1 = Cw[cbase + 33 + jp];
                uint32_t c2 = Cw[cbase + 66 + jp], c3 = Cw[cbase + 99 + jp];
                acc[0][0] = dot2(a0, c0, acc[0][0]); acc[0][1] = dot2(a0, c1, acc[0][1]);
                acc[0][2] = dot2(a0, c2, acc[0][2]); acc[0][3] = dot2(a0, c3, acc[0][3]);
                acc[1][0] = dot2(a1, c0, acc[1][0]); acc[1][1] = dot2(a1, c1, acc[1][1]);
                acc[1][2] = dot2(a1, c2, acc[1][2]); acc[1][3] = dot2(a1, c3, acc[1][3]);
            }
            const float r0 = rs[t * RSW + i0], r1 = rs[t * RSW + i0 + 1];
            #pragma unroll
            for (int ii = 0; ii < 2; ++ii) {
                const float rv = ii ? r1 : r0;
                #pragma unroll
                for (int dd = 0; dd < 4; ++dd) {
                    const int row = (i0 + ii) * 16 + d0 + dd;
                    stg[stg_idx(row, t)] = __builtin_bit_cast(uint32_t, acc[ii][dd] * rv);
                }
            }
        }
        __syncthreads();

        // ---- P4: t-coalesced 64B-row global writes ----
        if (tid < 512) {
            const int base = stg_idx(tid, 0);
            float ov[16];
            #pragma unroll
            for (int u = 0; u < 16; ++u) ov[u] = __builtin_bit_cast(float, stg[base + u]);
            float* op = out + ((size_t)b * 1024 + k * 512 + tid) * (size_t)T_ + t0;
            *(float4*)(op + 0)  = make_float4(ov[ 0], ov[ 1], ov[ 2], ov[ 3]);
            *(float4*)(op + 4)  = make_float4(ov[ 4], ov[ 5], ov[ 6], ov[ 7]);
            *(float4*)(op + 8)  = make_float4(ov[ 8], ov[ 9], ov[10], ov[11]);
            *(float4*)(op + 12) = make_float4(ov[12], ov[13], ov[14], ov[15]);
        } else {
            const int q  = tid - 512;
            const int j  = q & 63;
            const int i0 = (q >> 6) * 4;         // 0,4,..,28
            float* attn_base = out + (size_t)4 * 1024 * (size_t)T_;
            #pragma unroll
            for (int ii = 0; ii < 4; ++ii) {
                const int i = i0 + ii;
                float av[16];
                #pragma unroll
                for (int u = 0; u < 16; ++u)
                    av[u] = h2f(ACs[u * ATS + i * AIS + j]) * rs[u * RSW + i];
                float* tp2 = attn_base + (((size_t)bk * 32 + i) * 64 + j) * (size_t)T_ + t0;
                *(float4*)(tp2 + 0)  = make_float4(av[ 0], av[ 1], av[ 2], av[ 3]);
                *(float4*)(tp2 + 4)  = make_float4(av[ 4], av[ 5], av[ 6], av[ 7]);
                *(float4*)(tp2 + 8)  = make_float4(av[ 8], av[ 9], av[10], av[11]);
                *(float4*)(tp2 + 12) = make_float4(av[12], av[13], av[14], av[15]);
            }
        }
        __syncthreads();
    }
}

extern "C" void kernel_launch(void* const* d_in, const int* in_sizes, int n_in,
                              void* d_out, int out_size, void* d_ws, size_t ws_size,
                              hipStream_t stream) {
    const float* x  = (const float*)d_in[0];
    const float* W  = (const float*)d_in[1];
    const float* bs = (const float*)d_in[2];
    float* out = (float*)d_out;
    tamcad_kernel<<<dim3(256), dim3(1024), 0, stream>>>(x, W, bs, out);
}

// Round 8
// 287.982 us; speedup vs baseline: 1.2133x; 1.0488x over previous
//
#include <hip/hip_runtime.h>
#include <stdint.h>

#define T_   4096
#define XGS  76             // xs g-stride in u32 (9 u-slots * 8 d-pairs + 4 pad)
#define AIS  66             // As i-stride (u16): 64 j + 2 pad
#define ATS  2112           // As t-stride (u16) = 32*66
#define CTS  1056           // Cs t-stride (u16) = 16*66
#define CSB  (8*ATS)        // Cs base offset within ACs (u16) = 16896
#define RSW  33             // rs t-stride (f32)

typedef _Float16 h2 __attribute__((ext_vector_type(2)));

static __device__ __forceinline__ float dot2(uint32_t a, uint32_t b, float c) {
#if __has_builtin(__builtin_amdgcn_fdot2)
    return __builtin_amdgcn_fdot2(__builtin_bit_cast(h2, a), __builtin_bit_cast(h2, b), c, false);
#else
    h2 ha = __builtin_bit_cast(h2, a), hb = __builtin_bit_cast(h2, b);
    return fmaf((float)ha.x, (float)hb.x, fmaf((float)ha.y, (float)hb.y, c));
#endif
}
static __device__ __forceinline__ float exp2a(float x) {
#if __has_builtin(__builtin_amdgcn_exp2f)
    return __builtin_amdgcn_exp2f(x);
#else
    return exp2f(x);
#endif
}
static __device__ __forceinline__ uint16_t f2h(float f) {
    _Float16 h = (_Float16)f; return __builtin_bit_cast(uint16_t, h);
}
static __device__ __forceinline__ float h2f(uint16_t u) {
    return (float)__builtin_bit_cast(_Float16, u);
}
static __device__ __forceinline__ uint32_t pk2(float lo, float hi) {
    return __builtin_bit_cast(uint32_t, __builtin_amdgcn_cvt_pkrtz(lo, hi));
}
// out-stage skew: idx = 9*row + (row>>4) + col, col in 0..7.
// Injective: row step >= 9 while col spans 7; (row>>4) steps monotone.
// Max = 511*9 + 31 + 7 = 4637 < 4640.
static __device__ __forceinline__ int stg_idx(int row, int col) {
    return row * 9 + (row >> 4) + col;
}

__global__ __launch_bounds__(512, 2)
void tamcad_kernel(const float* __restrict__ x, const float* __restrict__ W,
                   const float* __restrict__ bias, float* __restrict__ out)
{
    __shared__ uint32_t stg[4640];           // 18,560B: out-stage; first 2432 words = xs
    __shared__ uint16_t ACs[CSB + 8*CTS];    // 50,688B: As[t][i][j] | Cs[t][d][j] (f16)
    __shared__ float    rs[8 * RSW];         // 1,056B: rcp(rowsum) per (t, i)

    uint32_t* xs32 = stg;

    const int tid   = threadIdx.x;
    const int bk    = blockIdx.x >> 6;   // 0..7
    const int chunk = blockIdx.x & 63;   // 0..63
    const int b     = bk >> 1;
    const int k     = bk & 1;

    // P1 mapping: 16 lanes per group, 6 o's per thread; also P0 (g, d)
    const int oq   = tid & 15;
    const int g    = tid >> 4;           // 0..31
    const int slot = oq >> 3;            // oq<8 (o<48): u=t ; else u=t+1
    const int dl   = oq;                 // P0 d-lane

    // ---- W rows as packed f16 pairs (6 x 8 u32), bias, store routing ----
    uint32_t wp2[6][8];
    float breg[6];
    int sbase[6], sstr[6]; bool isl[6];
    #pragma unroll
    for (int r = 0; r < 6; ++r) {
        const int o = oq * 6 + r;
        const float4* wp = reinterpret_cast<const float4*>(W + (((size_t)(k * 32 + g)) * 96 + o) * 16);
        float4 w0 = wp[0], w1 = wp[1], w2 = wp[2], w3 = wp[3];
        wp2[r][0] = pk2(w0.x, w0.y); wp2[r][1] = pk2(w0.z, w0.w);
        wp2[r][2] = pk2(w1.x, w1.y); wp2[r][3] = pk2(w1.z, w1.w);
        wp2[r][4] = pk2(w2.x, w2.y); wp2[r][5] = pk2(w2.z, w2.w);
        wp2[r][6] = pk2(w3.x, w3.y); wp2[r][7] = pk2(w3.z, w3.w);
        breg[r] = bias[(k * 32 + g) * 96 + o];
        if (o < 32)      { isl[r] = true;  sbase[r] = g * AIS + o;               sstr[r] = ATS; }
        else if (o < 48) { isl[r] = false; sbase[r] = CSB + (o - 32) * AIS + g;  sstr[r] = CTS; }
        else if (o < 80) { isl[r] = true;  sbase[r] = g * AIS + (o - 16);        sstr[r] = ATS; }
        else             { isl[r] = false; sbase[r] = CSB + (o - 80) * AIS + 32 + g; sstr[r] = CTS; }
    }

    const float* xrow = x + ((size_t)b * 1024 + (size_t)(k * 32 + g) * 16 + dl) * (size_t)T_;

    // ---- first slab prefetch: 9 floats (t0..t0+8); chunk*64+8 <= 4040 always in-bounds ----
    float4 pA, pB; float pS;
    {
        const float* gp = xrow + chunk * 64;
        pA = *(const float4*)(gp + 0);
        pB = *(const float4*)(gp + 4);
        pS = gp[8];
    }

    for (int l = 0; l < 8; ++l) {
        const int t0 = chunk * 64 + l * 8;

        // ---- P0: pack f32 pairs -> f16, stage into xs[g][u][dpair] ----
        {
            float vals[9] = { pA.x, pA.y, pA.z, pA.w, pB.x, pB.y, pB.z, pB.w, pS };
            #pragma unroll
            for (int i = 0; i < 9; ++i) {
                float mine  = vals[i];
                float other = __shfl_xor(mine, 1);
                if (((i ^ dl) & 1) == 0) {       // even d-lane stores even u, odd stores odd
                    uint32_t pk = (dl & 1) ? pk2(other, mine) : pk2(mine, other);
                    xs32[g * XGS + i * 8 + (dl >> 1)] = pk;
                }
            }
        }
        __syncthreads();

        // ---- P1: y = W.x + b via dot2; store e' = exp(y)/16 (logit) or y (ctx) ----
        {
            float asum[8];
            #pragma unroll
            for (int q = 0; q < 8; ++q) {
                const uint32_t* xp = xs32 + g * XGS + (q + slot) * 8;
                uint4 xa = *(const uint4*)xp;
                uint4 xb = *(const uint4*)(xp + 4);
                uint32_t xw[8] = { xa.x, xa.y, xa.z, xa.w, xb.x, xb.y, xb.z, xb.w };
                float s = 0.0f;
                #pragma unroll
                for (int r = 0; r < 6; ++r) {
                    float a = breg[r];
                    #pragma unroll
                    for (int dd = 0; dd < 8; ++dd) a = dot2(wp2[r][dd], xw[dd], a);
                    // e' = 2^(y*log2e - 4) = exp(y)/16 : f16-safe to y ~ 13.9
                    const float ev = exp2a(fmaf(a, 1.44269504089f, -4.0f));
                    s += isl[r] ? ev : 0.0f;
                    ACs[sbase[r] + q * sstr[r]] = f2h(isl[r] ? ev : a);
                }
                asum[q] = s;
            }
            #pragma unroll
            for (int sft = 1; sft < 16; sft <<= 1) {
                #pragma unroll
                for (int q = 0; q < 8; ++q) asum[q] += __shfl_xor(asum[q], sft);
            }
            if (oq == 0) {
                #pragma unroll
                for (int q = 0; q < 8; ++q)
                    rs[q * RSW + g] = __builtin_amdgcn_rcpf(asum[q]);
            }
        }
        __syncthreads();

        // issue next tile's global loads; land during P3/P4
        if (l < 7) {
            const int t0n = t0 + 8;
            const float* gp = xrow + t0n;
            pA = *(const float4*)(gp + 0);
            pB = *(const float4*)(gp + 4);
            pS = ((t0n + 8) < T_) ? gp[8] : 0.0f;
        }

        // ---- P3: out[i][d] = (sum_jp dot2(A,C)) * rinv ; one wave per t ----
        {
            const int t  = tid >> 6;             // 0..7
            const int r6 = tid & 63;
            const int i0 = (r6 & 15) * 2;        // 0,2,..,30
            const int d0 = (r6 >> 4) * 4;        // 0,4,8,12
            const uint32_t* Aw = (const uint32_t*)ACs;
            const uint32_t* Cw = (const uint32_t*)(ACs + CSB);
            const int abase = t * 1056 + i0 * 33;
            const int cbase = t * 528 + d0 * 33;
            float acc[2][4];
            #pragma unroll
            for (int ii = 0; ii < 2; ++ii)
                #pragma unroll
                for (int dd = 0; dd < 4; ++dd) acc[ii][dd] = 0.f;
            #pragma unroll 8
            for (int jp = 0; jp < 32; ++jp) {
                uint32_t a0 = Aw[abase + jp],      a1 = Aw[abase + 33 + jp];
                uint32_t c0 = Cw[cbase + jp],      c1 = Cw[cbase + 33 + jp];
                uint32_t c2 = Cw[cbase + 66 + jp], c3 = Cw[cbase + 99 + jp];
                acc[0][0] = dot2(a0, c0, acc[0][0]); acc[0][1] = dot2(a0, c1, acc[0][1]);
                acc[0][2] = dot2(a0, c2, acc[0][2]); acc[0][3] = dot2(a0, c3, acc[0][3]);
                acc[1][0] = dot2(a1, c0, acc[1][0]); acc[1][1] = dot2(a1, c1, acc[1][1]);
                acc[1][2] = dot2(a1, c2, acc[1][2]); acc[1][3] = dot2(a1, c3, acc[1][3]);
            }
            const float r0 = rs[t * RSW + i0], r1 = rs[t * RSW + i0 + 1];
            #pragma unroll
            for (int ii = 0; ii < 2; ++ii) {
                const float rv = ii ? r1 : r0;
                #pragma unroll
                for (int dd = 0; dd < 4; ++dd) {
                    const int row = (i0 + ii) * 16 + d0 + dd;
                    stg[stg_idx(row, t)] = __builtin_bit_cast(uint32_t, acc[ii][dd] * rv);
                }
            }
        }
        __syncthreads();

        // ---- P4: t-coalesced 32B-row global writes (1 out row + 4 attn rows / thread) ----
        {
            const int base = stg_idx(tid, 0);
            float ov[8];
            #pragma unroll
            for (int u = 0; u < 8; ++u) ov[u] = __builtin_bit_cast(float, stg[base + u]);
            float* op = out + ((size_t)b * 1024 + k * 512 + tid) * (size_t)T_ + t0;
            *(float4*)(op + 0) = make_float4(ov[0], ov[1], ov[2], ov[3]);
            *(float4*)(op + 4) = make_float4(ov[4], ov[5], ov[6], ov[7]);

            const int j   = tid & 63;
            const int i0a = (tid >> 6) * 4;      // 0,4,..,28
            float* attn_base = out + (size_t)4 * 1024 * (size_t)T_;
            #pragma unroll
            for (int ii = 0; ii < 4; ++ii) {
                const int i = i0a + ii;
                float av[8];
                #pragma unroll
                for (int u = 0; u < 8; ++u)
                    av[u] = h2f(ACs[u * ATS + i * AIS + j]) * rs[u * RSW + i];
                float* tp2 = attn_base + (((size_t)bk * 32 + i) * 64 + j) * (size_t)T_ + t0;
                *(float4*)(tp2 + 0) = make_float4(av[0], av[1], av[2], av[3]);
                *(float4*)(tp2 + 4) = make_float4(av[4], av[5], av[6], av[7]);
            }
        }
        __syncthreads();
    }
}

extern "C" void kernel_launch(void* const* d_in, const int* in_sizes, int n_in,
                              void* d_out, int out_size, void* d_ws, size_t ws_size,
                              hipStream_t stream) {
    const float* x  = (const float*)d_in[0];
    const float* W  = (const float*)d_in[1];
    const float* bs = (const float*)d_in[2];
    float* out = (float*)d_out;
    tamcad_kernel<<<dim3(512), dim3(512), 0, stream>>>(x, W, bs, out);
}

// Round 9
// 285.601 us; speedup vs baseline: 1.2234x; 1.0083x over previous
//
#include <hip/hip_runtime.h>
#include <stdint.h>

#define T_    4096
#define XGS   74      // xs g-stride (u32): 9 u-slots * 8 d-pairs + 2 pad
#define AIS32 33      // As32 i-stride (u32): 32 j-pairs + 1 pad
#define ATS32 1056    // As32 t-stride (u32) = 32*33
#define CTS16 1056    // Cs   t-stride (u16) = 16*66
#define RSW   33      // rs t-stride (f32)

typedef _Float16 h2 __attribute__((ext_vector_type(2)));

static __device__ __forceinline__ float dot2(uint32_t a, uint32_t b, float c) {
#if __has_builtin(__builtin_amdgcn_fdot2)
    return __builtin_amdgcn_fdot2(__builtin_bit_cast(h2, a), __builtin_bit_cast(h2, b), c, false);
#else
    h2 ha = __builtin_bit_cast(h2, a), hb = __builtin_bit_cast(h2, b);
    return fmaf((float)ha.x, (float)hb.x, fmaf((float)ha.y, (float)hb.y, c));
#endif
}
static __device__ __forceinline__ float exp2a(float x) {
#if __has_builtin(__builtin_amdgcn_exp2f)
    return __builtin_amdgcn_exp2f(x);
#else
    return exp2f(x);
#endif
}
static __device__ __forceinline__ uint16_t f2h(float f) {
    _Float16 h = (_Float16)f; return __builtin_bit_cast(uint16_t, h);
}
static __device__ __forceinline__ float h2f(uint16_t u) {
    return (float)__builtin_bit_cast(_Float16, u);
}
static __device__ __forceinline__ uint32_t pk2(float lo, float hi) {
    return __builtin_bit_cast(uint32_t, __builtin_amdgcn_cvt_pkrtz(lo, hi));
}
// out-stage (u32 = f16 d-pair): idx = 9*rp + 2*(rp>>4) + t, t in 0..7.
// Injective: rp step >= 9 > t span 7; max = 9*255 + 30 + 7 = 2332 < 2336.
static __device__ __forceinline__ int stg_ix(int rp, int t) {
    return rp * 9 + 2 * (rp >> 4) + t;
}

__global__ __launch_bounds__(512, 2)
void tamcad_kernel(const float* __restrict__ x, const float* __restrict__ W,
                   const float* __restrict__ bias, float* __restrict__ out)
{
    __shared__ uint32_t As32[8448];   // 33,792B: e' j-pairs, [t8][i32][jp33]
    __shared__ uint32_t Cs32[4224];   // 16,896B: y (f16), u16 view [t8][d16][j66]
    __shared__ uint32_t xs32[2368];   //  9,472B: x f16 d-pairs, [g32][u9][dp8]
    __shared__ uint32_t stg [2336];   //  9,344B: out staging, f16 d-pairs
    __shared__ float    rs  [264];    //  1,056B: rcp(rowsum) [t8][i33]
    uint16_t* Cs16 = (uint16_t*)Cs32;

    const int tid   = threadIdx.x;
    const int bk    = blockIdx.x >> 6;   // 0..7
    const int chunk = blockIdx.x & 63;   // 0..63
    const int b     = bk >> 1;
    const int k     = bk & 1;

    const int oq   = tid & 15;           // P1 o-slice / P0 d-lane
    const int g    = tid >> 4;           // group 0..31
    const int slot = oq >> 3;            // 0: u=t (o<48), 1: u=t+1 (o>=48)

    // ---- W as packed f16 d-pairs, bias, routing (pairs are category-pure) ----
    uint32_t wp2[6][8]; float breg[6]; bool isl[6];
    int cofs[6]; int aofs[3]; bool acat[3];
    #pragma unroll
    for (int r = 0; r < 6; ++r) {
        const int o = oq * 6 + r;
        const float4* wp = reinterpret_cast<const float4*>(W + (((size_t)(k*32+g))*96 + o)*16);
        float4 w0 = wp[0], w1 = wp[1], w2 = wp[2], w3 = wp[3];
        wp2[r][0] = pk2(w0.x, w0.y); wp2[r][1] = pk2(w0.z, w0.w);
        wp2[r][2] = pk2(w1.x, w1.y); wp2[r][3] = pk2(w1.z, w1.w);
        wp2[r][4] = pk2(w2.x, w2.y); wp2[r][5] = pk2(w2.z, w2.w);
        wp2[r][6] = pk2(w3.x, w3.y); wp2[r][7] = pk2(w3.z, w3.w);
        breg[r] = bias[(k*32+g)*96 + o];
        cofs[r] = 0;
        if (o < 32)       isl[r] = true;
        else if (o < 48) { isl[r] = false; cofs[r] = (o-32)*66 + g; }
        else if (o < 80)  isl[r] = true;
        else             { isl[r] = false; cofs[r] = (o-80)*66 + 32 + g; }
    }
    #pragma unroll
    for (int p = 0; p < 3; ++p) {
        const int oe = oq*6 + 2*p;
        if (oe < 32)                   { acat[p] = true;  aofs[p] = g*AIS32 + (oe >> 1); }
        else if (oe >= 48 && oe < 80)  { acat[p] = true;  aofs[p] = g*AIS32 + ((oe-16) >> 1); }
        else                           { acat[p] = false; aofs[p] = 0; }
    }

    const float* xrow = x + ((size_t)b*1024 + (size_t)(k*32+g)*16 + oq) * (size_t)T_;

    // prologue: issue loads for tile 0 (9 floats; chunk*64+8 <= 4040 in-bounds)
    float4 pA, pB; float pS;
    {
        const float* gp = xrow + chunk*64;
        pA = *(const float4*)gp; pB = *(const float4*)(gp + 4); pS = gp[8];
    }

    for (int l = 0; l <= 8; ++l) {
        const int t0p = chunk*64 + (l-1)*8;   // tile being drained (valid when l>0)

        // ================= Phase A =================
        if (l > 0) {
            if (tid >= 256) {
                // ---- P4a: attn global writes for tile l-1 (conflict-free u32 reads)
                const int q = tid - 256, j = q & 63, jb = j >> 1, jh = j & 1;
                float* attn_base = out + (size_t)4*1024*(size_t)T_;
                #pragma unroll
                for (int rr = 0; rr < 8; ++rr) {
                    const int i = (q >> 6) + 4*rr;
                    float av[8];
                    #pragma unroll
                    for (int u = 0; u < 8; ++u) {
                        uint32_t w = As32[u*ATS32 + i*AIS32 + jb];
                        av[u] = h2f(jh ? (uint16_t)(w >> 16) : (uint16_t)(w & 0xFFFF))
                              * rs[u*RSW + i];
                    }
                    float* tp2 = attn_base + (((size_t)bk*32 + i)*64 + j)*(size_t)T_ + t0p;
                    *(float4*)(tp2+0) = make_float4(av[0],av[1],av[2],av[3]);
                    *(float4*)(tp2+4) = make_float4(av[4],av[5],av[6],av[7]);
                }
            } else {
                // ---- P3: out[i,d,t] = rinv * sum_j e'[i,j] y[j,d]; acc[4][4]
                const int t  = tid >> 5;
                const int r5 = tid & 31;
                const int i0 = (r5 >> 2) * 4;
                const int d0 = (r5 & 3) * 4;
                const int ab = t*ATS32 + i0*AIS32;
                const int cb = t*528 + d0*33;
                float acc[4][4];
                #pragma unroll
                for (int ii = 0; ii < 4; ++ii)
                    #pragma unroll
                    for (int dd = 0; dd < 4; ++dd) acc[ii][dd] = 0.f;
                #pragma unroll 4
                for (int jp = 0; jp < 32; ++jp) {
                    uint32_t a0 = As32[ab+jp],    a1 = As32[ab+33+jp];
                    uint32_t a2 = As32[ab+66+jp], a3 = As32[ab+99+jp];
                    uint32_t c0 = Cs32[cb+jp],    c1 = Cs32[cb+33+jp];
                    uint32_t c2 = Cs32[cb+66+jp], c3 = Cs32[cb+99+jp];
                    acc[0][0]=dot2(a0,c0,acc[0][0]); acc[0][1]=dot2(a0,c1,acc[0][1]);
                    acc[0][2]=dot2(a0,c2,acc[0][2]); acc[0][3]=dot2(a0,c3,acc[0][3]);
                    acc[1][0]=dot2(a1,c0,acc[1][0]); acc[1][1]=dot2(a1,c1,acc[1][1]);
                    acc[1][2]=dot2(a1,c2,acc[1][2]); acc[1][3]=dot2(a1,c3,acc[1][3]);
                    acc[2][0]=dot2(a2,c0,acc[2][0]); acc[2][1]=dot2(a2,c1,acc[2][1]);
                    acc[2][2]=dot2(a2,c2,acc[2][2]); acc[2][3]=dot2(a2,c3,acc[2][3]);
                    acc[3][0]=dot2(a3,c0,acc[3][0]); acc[3][1]=dot2(a3,c1,acc[3][1]);
                    acc[3][2]=dot2(a3,c2,acc[3][2]); acc[3][3]=dot2(a3,c3,acc[3][3]);
                }
                #pragma unroll
                for (int ii = 0; ii < 4; ++ii) {
                    const float rv = rs[t*RSW + i0 + ii];
                    const int rp = (i0+ii)*8 + (d0 >> 1);
                    stg[stg_ix(rp,   t)] = pk2(acc[ii][0]*rv, acc[ii][1]*rv);
                    stg[stg_ix(rp+1, t)] = pk2(acc[ii][2]*rv, acc[ii][3]*rv);
                }
            }
        }
        if (l < 8) {
            // ---- P0: stage tile l into xs (f16 d-pairs via lane-xor)
            float vals[9] = { pA.x,pA.y,pA.z,pA.w, pB.x,pB.y,pB.z,pB.w, pS };
            #pragma unroll
            for (int i = 0; i < 9; ++i) {
                float mine  = vals[i];
                float other = __shfl_xor(mine, 1);
                if (((i ^ oq) & 1) == 0) {
                    uint32_t pk = (oq & 1) ? pk2(other, mine) : pk2(mine, other);
                    xs32[g*XGS + i*8 + (oq >> 1)] = pk;
                }
            }
            if (l < 7) {   // issue tile l+1 loads; fly across B1 + phase B + next P3
                const int t0n = chunk*64 + (l+1)*8;
                const float* gp = xrow + t0n;
                pA = *(const float4*)gp; pB = *(const float4*)(gp + 4);
                pS = ((t0n + 8) < T_) ? gp[8] : 0.0f;
            }
        }
        __syncthreads();

        // ================= Phase B =================
        if (l > 0) {
            // ---- P4b: out global writes (issued first, drain under P1)
            const int rp = tid >> 1, hi = tid & 1, base = stg_ix(rp, 0);
            float ov[8];
            #pragma unroll
            for (int u = 0; u < 8; ++u) {
                uint32_t w = stg[base + u];
                ov[u] = h2f(hi ? (uint16_t)(w >> 16) : (uint16_t)(w & 0xFFFF));
            }
            float* op = out + ((size_t)b*1024 + k*512 + tid)*(size_t)T_ + t0p;
            *(float4*)(op+0) = make_float4(ov[0],ov[1],ov[2],ov[3]);
            *(float4*)(op+4) = make_float4(ov[4],ov[5],ov[6],ov[7]);
        }
        if (l < 8) {
            // ---- P1: y = W.x + b (dot2); no-max softmax; A as u32 pairs
            float asum[8];
            #pragma unroll
            for (int q = 0; q < 8; ++q) {
                const uint32_t* xp = xs32 + g*XGS + (q + slot)*8;
                uint4 xa = *(const uint4*)xp;
                uint4 xb = *(const uint4*)(xp + 4);
                uint32_t xw[8] = { xa.x,xa.y,xa.z,xa.w, xb.x,xb.y,xb.z,xb.w };
                float v[6]; float s = 0.f;
                #pragma unroll
                for (int r = 0; r < 6; ++r) {
                    float y = breg[r];
                    #pragma unroll
                    for (int dd = 0; dd < 8; ++dd) y = dot2(wp2[r][dd], xw[dd], y);
                    // e' = 2^(y*log2e - 4) = exp(y)/16 (f16-safe to y ~ 13.9)
                    const float e = exp2a(fmaf(y, 1.44269504089f, -4.0f));
                    v[r] = isl[r] ? e : y;
                    s   += isl[r] ? e : 0.f;
                }
                #pragma unroll
                for (int p = 0; p < 3; ++p) {
                    if (acat[p]) {
                        As32[q*ATS32 + aofs[p]] = pk2(v[2*p], v[2*p+1]);
                    } else {
                        Cs16[q*CTS16 + cofs[2*p]]   = f2h(v[2*p]);
                        Cs16[q*CTS16 + cofs[2*p+1]] = f2h(v[2*p+1]);
                    }
                }
                asum[q] = s;
            }
            #pragma unroll
            for (int sft = 1; sft < 16; sft <<= 1) {
                #pragma unroll
                for (int q = 0; q < 8; ++q) asum[q] += __shfl_xor(asum[q], sft);
            }
            if (oq == 0) {
                #pragma unroll
                for (int q = 0; q < 8; ++q)
                    rs[q*RSW + g] = __builtin_amdgcn_rcpf(asum[q]);
            }
        }
        if (l < 8) __syncthreads();
    }
}

extern "C" void kernel_launch(void* const* d_in, const int* in_sizes, int n_in,
                              void* d_out, int out_size, void* d_ws, size_t ws_size,
                              hipStream_t stream) {
    const float* x  = (const float*)d_in[0];
    const float* W  = (const float*)d_in[1];
    const float* bs = (const float*)d_in[2];
    float* out = (float*)d_out;
    tamcad_kernel<<<dim3(512), dim3(512), 0, stream>>>(x, W, bs, out);
}